// Round 13
// baseline (128.025 us; speedup 1.0000x reference)
//
#include <hip/hip_runtime.h>
#include <hip/hip_bf16.h>
#include <math.h>

#define B_SZ 8192
#define I_SZ 1024
#define O_SZ 1024
#define NCP  6

typedef __attribute__((ext_vector_type(8))) short bf16x8;
typedef __attribute__((ext_vector_type(4))) float f32x4;

__device__ __forceinline__ unsigned short f2bf(float f) {
  union { float f; unsigned int u; } v; v.f = f;
  unsigned int u = v.u;
  u += 0x7FFFu + ((u >> 16) & 1u);   // round-to-nearest-even
  return (unsigned short)(u >> 16);
}

__global__ void cvt_f32_to_bf16(const float* __restrict__ src,
                                unsigned short* __restrict__ dst, int n4) {
  int idx = blockIdx.x * blockDim.x + threadIdx.x;
  int stride = gridDim.x * blockDim.x;
  for (int i = idx; i < n4; i += stride) {
    float4 v = reinterpret_cast<const float4*>(src)[i];
    ushort4 o;
    o.x = f2bf(v.x); o.y = f2bf(v.y); o.z = f2bf(v.z); o.w = f2bf(v.w);
    reinterpret_cast<ushort4*>(dst)[i] = o;
  }
}

__device__ __forceinline__ void gload_lds16(const void* g, void* l) {
  __builtin_amdgcn_global_load_lds(
      (const __attribute__((address_space(1))) void*)g,
      (__attribute__((address_space(3))) void*)l, 16, 0, 0);
}

#define BM 128
#define BN 128
#define BK 64
#define NT 96    // 6 j-chunks x 16 K-tiles

// out[b,o] = sum_j c[b,j] * ( sum_i W[j,o,i]*x[b,i] + bias[j,o] )
// R12's verified body (reg-dbuf fragments, 1 barrier/tile, part[] AGPR
// chain folded per j-chunk, both-sides XOR swizzle) at 128x128 / 4 waves /
// NBUF=2 (67KB LDS) => TWO blocks per CU: independent barrier schedules
// interleave, covering the ~900cy/tile of exposed LDS latency that 2
// lockstep waves/SIMD could not (R12 = m97-plateau, 37.5% MfmaUtil).
// Depth-1 staging: STAGE(t+1,buf^1) at tile top (safe: issued after the
// barrier that closed tile t-1's reads of buf^1), vmcnt(0)+s_barrier at
// tile end -- the drain overlaps the co-resident block's compute.
__global__ __launch_bounds__(256, 2) void pfl_gemm(
    const unsigned short* __restrict__ xb,
    const unsigned short* __restrict__ wb,
    const float* __restrict__ phase,
    const float* __restrict__ bias,
    float* __restrict__ out) {
  __shared__ __align__(16) unsigned short Abuf[2][BM * BK];  // 2x16 KB
  __shared__ __align__(16) unsigned short Bbuf[2][BN * BK];  // 2x16 KB
  __shared__ __align__(16) float c4[NCP][BM];                // 3 KB

  const int nbn = O_SZ / BN;  // 8
  int bid = (int)blockIdx.x;  // 512 blocks (divisible by 8)
  int swz = (bid & 7) * 64 + (bid >> 3);  // bijective XCD remap (cpx=64)
  int brow = (swz / nbn) * BM;
  int bcol = (swz % nbn) * BN;

  int tid = (int)threadIdx.x;
  int lane = tid & 63;
  int wid = tid >> 6;        // 0..3
  int wr = wid >> 1;         // 0..1 (M)
  int wc = wid & 1;          // 0..1 (N)

  // ---- Catmull-Rom coefficients, layout [j][row] for vectorized folds ----
  if (tid < BM) {
    float ph = phase[brow + tid];
    const float two_pi = 6.2831855f;
    float pm = fmodf(ph, two_pi);              // ph >= 0 -> trunc == floor mod
    float pos = pm * (float)(6.0 / 6.283185307179586);
    float base = floorf(pos);
    int bi = (int)base;
    float t = pos - base;
    float t2 = t * t, t3 = t2 * t;
    float w0 = -0.5f * t + t2 - 0.5f * t3;
    float w1 = 1.0f - 2.5f * t2 + 1.5f * t3;
    float w2 = 0.5f * t + 2.0f * t2 - 1.5f * t3;
    float w3 = -0.5f * t2 + 0.5f * t3;
    float cc[NCP] = {0.f, 0.f, 0.f, 0.f, 0.f, 0.f};
    cc[((bi - 1) % NCP + NCP) % NCP] += w0;
    cc[(bi % NCP + NCP) % NCP]       += w1;
    cc[((bi + 1) % NCP + NCP) % NCP] += w2;
    cc[((bi + 2) % NCP + NCP) % NCP] += w3;
    for (int j = 0; j < NCP; ++j) c4[j][tid] = cc[j];
  }

  f32x4 acc[4][4];   // folded result (VALU-touched once per 16 tiles)
  f32x4 part[4][4];  // pure MFMA chain within a j-chunk (AGPR-resident)
#pragma unroll
  for (int m = 0; m < 4; ++m)
#pragma unroll
    for (int n = 0; n < 4; ++n) {
      acc[m][n] = (f32x4){0.f, 0.f, 0.f, 0.f};
      part[m][n] = (f32x4){0.f, 0.f, 0.f, 0.f};
    }

  // staging: lane l -> LDS row (base + l>>3), linear 16B slot (l&7);
  // global source column pre-swizzled (slot xor row&7), rule #21.
  int swzcol = ((lane & 7) ^ (lane >> 3)) * 8;
  const unsigned short* xsrc =
      xb + (size_t)(brow + wid * 8 + (lane >> 3)) * I_SZ + swzcol;
  const unsigned short* wsrc =
      wb + (size_t)(bcol + wid * 8 + (lane >> 3)) * I_SZ + swzcol;

  // read-side swizzled base: slot = chunk ^ (row&7); row&7 == lane&7 here
  int lbase = (lane & 15) * 128 + (((lane >> 4) ^ (lane & 7)) & 7) * 16;

  auto STAGE = [&](int t, int b) {   // 8 DMAs/wave: 4 A + 4 B (32-row stride)
    int ks = (t & 15) * 64;
    int j = t >> 4;
    const unsigned short* xs = xsrc + ks;
    const unsigned short* ws = wsrc + (size_t)j * O_SZ * I_SZ + ks;
    unsigned short* Ad = &Abuf[b][(wid * 8) * BK];
    unsigned short* Bd = &Bbuf[b][(wid * 8) * BK];
#pragma unroll
    for (int p = 0; p < 4; ++p)
      gload_lds16(xs + (size_t)p * 32 * I_SZ, Ad + p * 32 * BK);
#pragma unroll
    for (int p = 0; p < 4; ++p)
      gload_lds16(ws + (size_t)p * 32 * I_SZ, Bd + p * 32 * BK);
  };

  // prologue: tile 0 resident; c4 published
  STAGE(0, 0);
  asm volatile("s_waitcnt vmcnt(0)" ::: "memory");
  __builtin_amdgcn_sched_barrier(0);
  __syncthreads();

  int cur = 0;
  for (int t = 0; t < NT; ++t) {
    const char* Ab = (const char*)&Abuf[cur][0];
    const char* Bb = (const char*)&Bbuf[cur][0];

    // ---- stage t+1 into the other buffer (after the barrier that closed
    //      tile t-1's reads of it); lands under this tile's compute ----
    if (t + 1 < NT) STAGE(t + 1, cur ^ 1);

    // ---- kk=0 fragment reads ----
    bf16x8 af0[4], bf0[4], af1[4], bf1[4];
#pragma unroll
    for (int m = 0; m < 4; ++m)
      af0[m] = *reinterpret_cast<const bf16x8*>(
          Ab + (wr * 64 + m * 16) * 128 + lbase);
#pragma unroll
    for (int n = 0; n < 4; ++n)
      bf0[n] = *reinterpret_cast<const bf16x8*>(
          Bb + (wc * 64 + n * 16) * 128 + lbase);
    asm volatile("s_waitcnt lgkmcnt(0)" ::: "memory");
    __builtin_amdgcn_sched_barrier(0);

    // ---- issue kk=1 reads: they fly under MFMA0 ----
#pragma unroll
    for (int m = 0; m < 4; ++m)
      af1[m] = *reinterpret_cast<const bf16x8*>(
          Ab + (wr * 64 + m * 16) * 128 + (lbase ^ 64));
#pragma unroll
    for (int n = 0; n < 4; ++n)
      bf1[n] = *reinterpret_cast<const bf16x8*>(
          Bb + (wc * 64 + n * 16) * 128 + (lbase ^ 64));
    __builtin_amdgcn_sched_barrier(0);  // pin kk1 issue before MFMA0

    __builtin_amdgcn_s_setprio(1);
#pragma unroll
    for (int m = 0; m < 4; ++m)
#pragma unroll
      for (int n = 0; n < 4; ++n)
        part[m][n] = __builtin_amdgcn_mfma_f32_16x16x32_bf16(
            af0[m], bf0[n], part[m][n], 0, 0, 0);
    __builtin_amdgcn_s_setprio(0);

    asm volatile("s_waitcnt lgkmcnt(0)" ::: "memory");  // kk1 frags landed
    __builtin_amdgcn_sched_barrier(0);

    __builtin_amdgcn_s_setprio(1);
#pragma unroll
    for (int m = 0; m < 4; ++m)
#pragma unroll
      for (int n = 0; n < 4; ++n)
        part[m][n] = __builtin_amdgcn_mfma_f32_16x16x32_bf16(
            af1[m], bf1[n], part[m][n], 0, 0, 0);
    __builtin_amdgcn_s_setprio(0);

    if ((t & 15) == 15) {  // j-chunk boundary: acc += c[row,j] * part
      int j = t >> 4;
#pragma unroll
      for (int m = 0; m < 4; ++m) {
        f32x4 cv = *reinterpret_cast<const f32x4*>(
            &c4[j][wr * 64 + m * 16 + (lane >> 4) * 4]);
#pragma unroll
        for (int n = 0; n < 4; ++n) {
          acc[m][n] += cv * part[m][n];
          part[m][n] = (f32x4){0.f, 0.f, 0.f, 0.f};
        }
      }
    }

    // ---- tile boundary: drain own DMAs (t+1 resident) + single barrier;
    //      the other block on this CU computes through our drain ----
    asm volatile("s_waitcnt vmcnt(0)" ::: "memory");
    __builtin_amdgcn_sched_barrier(0);
    __builtin_amdgcn_s_barrier();
    cur ^= 1;
  }

  // ---- epilogue: bias mix + store (f32) ----
#pragma unroll
  for (int n = 0; n < 4; ++n) {
    int col = bcol + wc * 64 + n * 16 + (lane & 15);
    float b6[NCP];
#pragma unroll
    for (int j = 0; j < NCP; ++j) b6[j] = bias[j * O_SZ + col];
#pragma unroll
    for (int m = 0; m < 4; ++m) {
#pragma unroll
      for (int r = 0; r < 4; ++r) {
        int rloc = wr * 64 + m * 16 + (lane >> 4) * 4 + r;
        float s = 0.f;
#pragma unroll
        for (int j = 0; j < NCP; ++j) s += c4[j][rloc] * b6[j];
        out[(size_t)(brow + rloc) * O_SZ + col] = acc[m][n][r] + s;
      }
    }
  }
}

extern "C" void kernel_launch(void* const* d_in, const int* in_sizes, int n_in,
                              void* d_out, int out_size, void* d_ws, size_t ws_size,
                              hipStream_t stream) {
  (void)in_sizes; (void)n_in; (void)out_size; (void)ws_size;
  const float* x     = (const float*)d_in[0];  // [B, I]
  const float* phase = (const float*)d_in[1];  // [B]
  const float* w     = (const float*)d_in[2];  // [C, O, I]
  const float* bias  = (const float*)d_in[3];  // [C, O]
  float* out = (float*)d_out;                  // [B, O] f32

  unsigned short* xb = (unsigned short*)d_ws;                       // 16 MB
  unsigned short* wb = (unsigned short*)((char*)d_ws +
                        (size_t)B_SZ * I_SZ * sizeof(unsigned short));  // 12 MB

  cvt_f32_to_bf16<<<2048, 256, 0, stream>>>(x, xb, B_SZ * I_SZ / 4);
  cvt_f32_to_bf16<<<1536, 256, 0, stream>>>(w, wb, NCP * O_SZ * I_SZ / 4);

  dim3 grid((B_SZ / BM) * (O_SZ / BN));  // 64*8 = 512
  pfl_gemm<<<grid, 256, 0, stream>>>(xb, wb, phase, bias, out);
}